// Round 10
// baseline (279.066 us; speedup 1.0000x reference)
//
#include <hip/hip_runtime.h>
#include <math.h>

#define N 16384
#define D 1024
#define EPSF 1e-8f
#define QSCALE 448.0f
#define NPAIRS 2080
#define PANB 262144  /* bytes per 256-row i8 row-major panel */
#define GRANB 262144 /* bytes per granule plane of xqT (16384 rows x 16B) */

typedef __attribute__((ext_vector_type(4))) int i32x4;
typedef unsigned int u32;
typedef unsigned long long u64;

// LDS: B ring-8 [0,128K) = 8 slots x 16KB; s_next [128K,+16)
#define LDS_TOT 131088

__device__ __forceinline__ void gload_lds16(const void* g, void* l) {
  __builtin_amdgcn_global_load_lds(
      (const __attribute__((address_space(1))) u32*)g,
      (__attribute__((address_space(3))) u32*)l, 16, 0, 0);
}

__device__ __forceinline__ u64 maxu64(u64 x, u64 y) { return x > y ? x : y; }

__device__ __forceinline__ void decode_pair(int t, int& a, int& b) {
  int aa = (int)((129.0 - sqrt(129.0 * 129.0 - 8.0 * (double)t)) * 0.5);
  if (aa < 0) aa = 0;
  if (aa > 63) aa = 63;
  while (((aa + 1) * 64 - ((aa + 1) * aa) / 2) <= t) ++aa;
  while ((aa * 64 - (aa * (aa - 1)) / 2) > t) --aa;
  a = aa;
  b = aa + (t - (aa * 64 - (aa * (aa - 1)) / 2));
}

// ---------- kernel 1: norms + i8 row-major xq + granule-major xqT ----------

__global__ __launch_bounds__(256) void k_normalize(
    const float* __restrict__ x, signed char* __restrict__ xq,
    signed char* __restrict__ xqT, float* __restrict__ norms,
    u64* __restrict__ best, int* __restrict__ ctr) {
  const int w = threadIdx.x >> 6, lane = threadIdx.x & 63;
  const int i = blockIdx.x * 4 + w;  // one wave per row
  if (threadIdx.x < 4) best[(size_t)blockIdx.x * 4 + threadIdx.x] = 0;
  if (blockIdx.x == 0 && threadIdx.x == 0) *ctr = 0;
  const float4* xi = (const float4*)(x + (size_t)i * D);
  float4 v[4];
  float s = 0.f;
#pragma unroll
  for (int t = 0; t < 4; ++t) {
    v[t] = xi[lane + t * 64];
    s += v[t].x * v[t].x + v[t].y * v[t].y + v[t].z * v[t].z + v[t].w * v[t].w;
  }
#pragma unroll
  for (int sh = 32; sh; sh >>= 1) s += __shfl_xor(s, sh, 64);
  const float nrm = sqrtf(s);
  if (lane == 0) norms[i] = nrm;
  const float qs = QSCALE / fmaxf(nrm, EPSF);
  u32* xo = (u32*)(xq + (size_t)i * D);
  u32* xoT = (u32*)xqT;
#pragma unroll
  for (int t = 0; t < 4; ++t) {
    const int q0 = __float2int_rn(fminf(fmaxf(v[t].x * qs, -127.f), 127.f));
    const int q1 = __float2int_rn(fminf(fmaxf(v[t].y * qs, -127.f), 127.f));
    const int q2 = __float2int_rn(fminf(fmaxf(v[t].z * qs, -127.f), 127.f));
    const int q3 = __float2int_rn(fminf(fmaxf(v[t].w * qs, -127.f), 127.f));
    const u32 val = (u32)(q0 & 0xff) | ((u32)(q1 & 0xff) << 8) |
                    ((u32)(q2 & 0xff) << 16) | ((u32)(q3 & 0xff) << 24);
    const int wrd = lane + t * 64;  // u32 word index along k
    xo[wrd] = val;
    xoT[((size_t)(wrd >> 2) * 16384 + (u32)i) * 4 + (wrd & 3)] = val;
  }
}

// ---------- kernel 2: group-4 de-lockstep i8 MFMA argmax ----------
// 256 blocks (1/CU), 512 thr = 8 waves (4M x 2N), per-wave C = 64x128.
// Work-steal 2080 symmetric pairs. A-fragments loaded straight from xqT
// (coalesced L2 reads, no LDS). B staged in an 8-slot LDS ring (16KB/slot),
// swizzled; stage target = tile+4. ONE barrier + ONE vmcnt(0) per 4 K-tiles:
// group g reads slots g*4..g*4+3 while staging slots g*4+4..+7 (disjoint for
// any intra-group wave skew) -> waves drift freely across 4 tiles, LDS-read
// bursts overlap MFMA across waves. 16 = 0 mod 8 keeps pairs seamless.

#define SGB(gaddr, daddr) \
  gload_lds16(xqB + (gaddr) + srcLane, lds + (daddr) + w * 1024)

#define TILE(T_)                                                               \
  {                                                                            \
    const char* aT = xqTB + aRowB + (size_t)((T_)*4) * GRANB;                  \
    const i32x4 aa0 = *(const i32x4*)(aT);                                     \
    const i32x4 aa1 = *(const i32x4*)(aT + 256);                               \
    const i32x4 aa2 = *(const i32x4*)(aT + 512);                               \
    const i32x4 aa3 = *(const i32x4*)(aT + 768);                               \
    if ((T_) < 12) {                                                           \
      const size_t bG = bPan + (size_t)(((T_) + 4) * 64);                      \
      SGB(bG, (((T_) + 4) & 7) * 16384);                                       \
      SGB(bG + 131072, (((T_) + 4) & 7) * 16384 + 8192);                       \
    } else if (hasNext) {                                                      \
      const size_t bG = bPanN + (size_t)(((T_)-12) * 64);                      \
      SGB(bG, (((T_) + 4) & 7) * 16384);                                       \
      SGB(bG + 131072, (((T_) + 4) & 7) * 16384 + 8192);                       \
    }                                                                          \
    i32x4 bb[4];                                                               \
    _Pragma("unroll") for (int n = 0; n < 4; ++n) bb[n] =                      \
        *(const i32x4*)(lds + ((T_)&7) * 16384 + bOff[n]);                     \
    __builtin_amdgcn_s_setprio(1);                                             \
    _Pragma("unroll") for (int n = 0; n < 4; ++n) {                            \
      acc[0][n] = __builtin_amdgcn_mfma_i32_16x16x64_i8(aa0, bb[n], acc[0][n], \
                                                        0, 0, 0);              \
      acc[1][n] = __builtin_amdgcn_mfma_i32_16x16x64_i8(aa1, bb[n], acc[1][n], \
                                                        0, 0, 0);              \
      acc[2][n] = __builtin_amdgcn_mfma_i32_16x16x64_i8(aa2, bb[n], acc[2][n], \
                                                        0, 0, 0);              \
      acc[3][n] = __builtin_amdgcn_mfma_i32_16x16x64_i8(aa3, bb[n], acc[3][n], \
                                                        0, 0, 0);              \
    }                                                                          \
    __builtin_amdgcn_s_setprio(0);                                             \
    _Pragma("unroll") for (int n = 0; n < 4; ++n) bb[n] =                      \
        *(const i32x4*)(lds + ((T_)&7) * 16384 + bOff[4 + n]);                 \
    __builtin_amdgcn_s_setprio(1);                                             \
    _Pragma("unroll") for (int n = 0; n < 4; ++n) {                            \
      acc[0][4 + n] = __builtin_amdgcn_mfma_i32_16x16x64_i8(                   \
          aa0, bb[n], acc[0][4 + n], 0, 0, 0);                                 \
      acc[1][4 + n] = __builtin_amdgcn_mfma_i32_16x16x64_i8(                   \
          aa1, bb[n], acc[1][4 + n], 0, 0, 0);                                 \
      acc[2][4 + n] = __builtin_amdgcn_mfma_i32_16x16x64_i8(                   \
          aa2, bb[n], acc[2][4 + n], 0, 0, 0);                                 \
      acc[3][4 + n] = __builtin_amdgcn_mfma_i32_16x16x64_i8(                   \
          aa3, bb[n], acc[3][4 + n], 0, 0, 0);                                 \
    }                                                                          \
    __builtin_amdgcn_s_setprio(0);                                             \
  }

#define GROUP(G_)                                                              \
  {                                                                            \
    __builtin_amdgcn_s_barrier();                                              \
    asm volatile("" ::: "memory");                                             \
    TILE(4 * (G_) + 0);                                                        \
    TILE(4 * (G_) + 1);                                                        \
    TILE(4 * (G_) + 2);                                                        \
    TILE(4 * (G_) + 3);                                                        \
    asm volatile("s_waitcnt vmcnt(0)" ::: "memory");                           \
  }

__global__ __launch_bounds__(512, 2) void k_argmax(
    const signed char* __restrict__ xq, const signed char* __restrict__ xqT,
    u64* __restrict__ best, int* __restrict__ ctr) {
  extern __shared__ char lds[];
  int* s_next = (int*)(lds + 131072);  // 2 parity slots
  const char* xqB = (const char*)xq;
  const char* xqTB = (const char*)xqT;
  const int tid = (int)threadIdx.x, lane = tid & 63, w = tid >> 6;
  const int wr = w >> 1, wc = w & 1;

  // B slot (16KB): 256 rows x 64B, 2 rows/128B line,
  // granule swizzle: inner = (((rr&1)<<6)|(q<<4)) ^ ((line&7)<<4)
  int bOff[8];
  const int q = lane >> 4, li = lane & 15;
#pragma unroll
  for (int nf = 0; nf < 8; ++nf) {
    const int rr = wc * 128 + nf * 16 + li;
    const int line = rr >> 1;
    bOff[nf] = line * 128 + ((((rr & 1) << 6) | (q << 4)) ^ ((line & 7) << 4));
  }
  // staging per-lane source offset (inverse swizzle; linear gload dest)
  const int posx = (lane & 7) ^ (lane >> 3);
  const int rrl = ((w * 8 + (lane >> 3)) << 1) | (posx >> 2);
  const int srcLane = rrl * 1024 + (posx & 3) * 16;

  const int rB2 = wr * 64 + (q << 2);
  const int cB2 = wc * 128 + li;

  // bootstrap: steal first two pairs
  if (tid == 0) {
    s_next[0] = atomicAdd(ctr, 1);
    s_next[1] = atomicAdd(ctr, 1);
  }
  __syncthreads();
  int pcur = s_next[0], pnext = s_next[1];
  __syncthreads();
  if (pcur >= NPAIRS) return;

  int a, b;
  decode_pair(pcur, a, b);
  size_t bPan = (size_t)b * PANB;
  // prologue: stage B tiles 0..3 into slots 0..3
  for (int p = 0; p < 4; ++p) {
    SGB(bPan + (size_t)(p * 64), p * 16384);
    SGB(bPan + (size_t)(p * 64) + 131072, p * 16384 + 8192);
  }
  asm volatile("s_waitcnt vmcnt(0)" ::: "memory");

  int par = 0;
  i32x4 acc[4][8];
  while (true) {
    const bool hasNext = (pnext < NPAIRS);
    int an = 0, bn = 0;
    if (hasNext) decode_pair(pnext, an, bn);
    const size_t bPanN = (size_t)bn * PANB;
    if (tid == 0) s_next[par] = atomicAdd(ctr, 1);  // steal pair-after-next
    const size_t aRowB =
        (size_t)q * GRANB + (size_t)(a * 256 + wr * 64 + li) * 16;

#pragma unroll
    for (int m = 0; m < 4; ++m)
#pragma unroll
      for (int n = 0; n < 8; ++n) acc[m][n] = (i32x4){0, 0, 0, 0};

    GROUP(0)
    GROUP(1)
    GROUP(2)
    GROUP(3)

    // ---- epilogue for pair (a,b): register folds + atomicMax publish ----
    const int aBase = a * 256, colBase = b * 256;
    // row-side: rows of a over cols of b
#pragma unroll
    for (int m = 0; m < 4; ++m)
#pragma unroll
      for (int r = 0; r < 4; ++r) {
        const int rl = rB2 + m * 16 + r;
        int pm = (int)0x80000000;
        if (a == b) {
#pragma unroll
          for (int nf = 0; nf < 8; ++nf) {
            int pv = (int)(((u32)acc[m][nf][r] << 3) | (u32)nf);
            if (rl == cB2 + nf * 16) pv = (int)0x80000000;
            pm = pm > pv ? pm : pv;
          }
        } else {
#pragma unroll
          for (int nf = 0; nf < 8; ++nf) {
            const int pv = (int)(((u32)acc[m][nf][r] << 3) | (u32)nf);
            pm = pm > pv ? pm : pv;
          }
        }
        const u32 mono = (u32)(pm >> 3) ^ 0x80000000u;
        u64 p = ((u64)mono << 32) | (u32)(colBase + cB2 + ((pm & 7) << 4));
#pragma unroll
        for (int sh = 1; sh < 16; sh <<= 1)
          p = maxu64(p, __shfl_xor(p, sh, 64));
        if (li == 0) atomicMax(best + (aBase + rl), p);
      }

    // col-side: rows of b, candidates = rows of a (skip on diagonal)
    if (a != b) {
#pragma unroll
      for (int nf = 0; nf < 8; ++nf) {
        int pv = (int)0x80000000;
#pragma unroll
        for (int m = 0; m < 4; ++m)
#pragma unroll
          for (int r = 0; r < 4; ++r) {
            const int c =
                (int)(((u32)acc[m][nf][r] << 6) | (u32)(m * 16 + q * 4 + r));
            pv = pv > c ? pv : c;
          }
        {
          const int o1 = __shfl_xor(pv, 16, 64);
          pv = pv > o1 ? pv : o1;
          const int o2 = __shfl_xor(pv, 32, 64);
          pv = pv > o2 ? pv : o2;
        }
        if (q == 0) {
          const int dot = pv >> 6;
          const int grow = aBase + wr * 64 + (pv & 63);
          const u64 pk = ((u64)((u32)dot ^ 0x80000000u) << 32) | (u32)grow;
          atomicMax(best + (colBase + cB2 + nf * 16), pk);
        }
      }
    }

    if (!hasNext) break;
    const int pnn = s_next[par];  // published by the group barriers
    pcur = pnext;
    a = an;
    b = bn;
    bPan = bPanN;
    pnext = pnn;
    par ^= 1;
  }
}

// ---------- kernel 3: exact fp32 distance + log ----------

__global__ __launch_bounds__(256) void k_dist(
    const float* __restrict__ x, const float* __restrict__ norms,
    const u64* __restrict__ best, float* __restrict__ logd) {
  const int w = threadIdx.x >> 6, lane = threadIdx.x & 63;
  const int i = blockIdx.x * 4 + w;
  const u64 p = best[i];
  const int j = (int)(p & 0xffffffffu);
  const float invi = 1.f / fmaxf(norms[i], EPSF);
  const float invj = 1.f / fmaxf(norms[j], EPSF);
  const float4* xi = (const float4*)(x + (size_t)i * D);
  const float4* xj = (const float4*)(x + (size_t)j * D);
  float s = 0.f;
#pragma unroll
  for (int t = 0; t < 4; ++t) {
    const float4 av = xi[lane + t * 64], bv = xj[lane + t * 64];
    float d;
    d = av.x * invi - bv.x * invj + EPSF; s += d * d;
    d = av.y * invi - bv.y * invj + EPSF; s += d * d;
    d = av.z * invi - bv.z * invj + EPSF; s += d * d;
    d = av.w * invi - bv.w * invj + EPSF; s += d * d;
  }
#pragma unroll
  for (int sh = 32; sh; sh >>= 1) s += __shfl_xor(s, sh, 64);
  if (lane == 0) logd[i] = logf(sqrtf(s) + EPSF);
}

// ---------- kernel 4: deterministic fixed-order mean ----------

__global__ __launch_bounds__(256) void k_final(const float* __restrict__ logd,
                                               float* __restrict__ out) {
  __shared__ double red[256];
  double s = 0.0;
  for (int i = threadIdx.x; i < N; i += 256) s += (double)logd[i];
  red[threadIdx.x] = s;
  __syncthreads();
  for (int sh = 128; sh; sh >>= 1) {
    if ((int)threadIdx.x < sh) red[threadIdx.x] += red[threadIdx.x + sh];
    __syncthreads();
  }
  if (threadIdx.x == 0) out[0] = (float)(-red[0] / (double)N);
}

// ---------- launch ----------

extern "C" void kernel_launch(void* const* d_in, const int* in_sizes, int n_in,
                              void* d_out, int out_size, void* d_ws,
                              size_t ws_size, hipStream_t stream) {
  const float* x = (const float*)d_in[0];
  float* out = (float*)d_out;
  char* ws = (char*)d_ws;

  // ws: xq 16MB | xqT 16MB | norms 64KB | best 128KB | logd 64KB | ctr 64B
  signed char* xq = (signed char*)ws;
  signed char* xqT = (signed char*)(ws + 16777216);
  float* norms = (float*)(ws + 33554432);
  u64* best = (u64*)(ws + 33619968);
  float* logd = (float*)(ws + 33751040);
  int* ctr = (int*)(ws + 33816576);

  k_normalize<<<N / 4, 256, 0, stream>>>(x, xq, xqT, norms, best, ctr);
  k_argmax<<<256, 512, LDS_TOT, stream>>>(xq, xqT, best, ctr);
  k_dist<<<N / 4, 256, 0, stream>>>(x, norms, best, logd);
  k_final<<<1, 256, 0, stream>>>(logd, out);
}

// Round 11
// 260.395 us; speedup vs baseline: 1.0717x; 1.0717x over previous
//
#include <hip/hip_runtime.h>
#include <math.h>

#define N 16384
#define D 1024
#define EPSF 1e-8f
#define QSCALE 448.0f
#define NPAIRS 2080
#define PANB 262144  /* bytes per 256-row i8 row-major panel */
#define GRANB 262144 /* bytes per granule plane of xqT (16384 rows x 16B) */

typedef __attribute__((ext_vector_type(4))) int i32x4;
typedef unsigned int u32;
typedef unsigned long long u64;

// LDS: B ring-4 [0,64K) = 4 slots x 16KB; s_next [64K,+16)
#define LDS_TOT 65552

__device__ __forceinline__ void gload_lds16(const void* g, void* l) {
  __builtin_amdgcn_global_load_lds(
      (const __attribute__((address_space(1))) u32*)g,
      (__attribute__((address_space(3))) u32*)l, 16, 0, 0);
}

__device__ __forceinline__ u64 maxu64(u64 x, u64 y) { return x > y ? x : y; }

__device__ __forceinline__ void decode_pair(int t, int& a, int& b) {
  int aa = (int)((129.0 - sqrt(129.0 * 129.0 - 8.0 * (double)t)) * 0.5);
  if (aa < 0) aa = 0;
  if (aa > 63) aa = 63;
  while (((aa + 1) * 64 - ((aa + 1) * aa) / 2) <= t) ++aa;
  while ((aa * 64 - (aa * (aa - 1)) / 2) > t) --aa;
  a = aa;
  b = aa + (t - (aa * 64 - (aa * (aa - 1)) / 2));
}

// ---------- kernel 1: norms + i8 row-major xq + granule-major xqT ----------

__global__ __launch_bounds__(256) void k_normalize(
    const float* __restrict__ x, signed char* __restrict__ xq,
    signed char* __restrict__ xqT, float* __restrict__ norms,
    u64* __restrict__ best, int* __restrict__ ctr) {
  const int w = threadIdx.x >> 6, lane = threadIdx.x & 63;
  const int i = blockIdx.x * 4 + w;  // one wave per row
  if (threadIdx.x < 4) best[(size_t)blockIdx.x * 4 + threadIdx.x] = 0;
  if (blockIdx.x == 0 && threadIdx.x == 0) *ctr = 0;
  const float4* xi = (const float4*)(x + (size_t)i * D);
  float4 v[4];
  float s = 0.f;
#pragma unroll
  for (int t = 0; t < 4; ++t) {
    v[t] = xi[lane + t * 64];
    s += v[t].x * v[t].x + v[t].y * v[t].y + v[t].z * v[t].z + v[t].w * v[t].w;
  }
#pragma unroll
  for (int sh = 32; sh; sh >>= 1) s += __shfl_xor(s, sh, 64);
  const float nrm = sqrtf(s);
  if (lane == 0) norms[i] = nrm;
  const float qs = QSCALE / fmaxf(nrm, EPSF);
  u32* xo = (u32*)(xq + (size_t)i * D);
  u32* xoT = (u32*)xqT;
#pragma unroll
  for (int t = 0; t < 4; ++t) {
    const int q0 = __float2int_rn(fminf(fmaxf(v[t].x * qs, -127.f), 127.f));
    const int q1 = __float2int_rn(fminf(fmaxf(v[t].y * qs, -127.f), 127.f));
    const int q2 = __float2int_rn(fminf(fmaxf(v[t].z * qs, -127.f), 127.f));
    const int q3 = __float2int_rn(fminf(fmaxf(v[t].w * qs, -127.f), 127.f));
    const u32 val = (u32)(q0 & 0xff) | ((u32)(q1 & 0xff) << 8) |
                    ((u32)(q2 & 0xff) << 16) | ((u32)(q3 & 0xff) << 24);
    const int wrd = lane + t * 64;  // u32 word index along k
    xo[wrd] = val;
    xoT[((size_t)(wrd >> 2) * 16384 + (u32)i) * 4 + (wrd & 3)] = val;
  }
}

// ---------- kernel 2: A-reg-prefetch + B-LDS i8 MFMA argmax ----------
// 256 blocks (1/CU), 512 thr = 8 waves (4M x 2N), per-wave C = 64x128.
// Work-steal 2080 symmetric pairs (a<=b), 16 K-tiles of 64 k each.
// A fragments: register double-buffer, prefetched from xqT (global/L2) one
// K-tile ahead -- VMEM pipe runs under MFMA, zero LDS traffic for A.
// B: ring-4 LDS (16KB slots, swizzled), staged 3 tiles ahead, 1 barrier +
// vmcnt(8) per K-tile. Per tile the wave issues [Apref(4), Bstage(2)];
// vmcnt(8) = B(t+2)2 + Apref(t+1)4 + B(t+3)2 keeps exactly those in flight.

#define SGB(gaddr, daddr) \
  gload_lds16(xqB + (gaddr) + srcLane, lds + (daddr) + w * 1024)

#define KT1(K_, AC, AN)                                                        \
  {                                                                            \
    __builtin_amdgcn_s_barrier();                                              \
    asm volatile("" ::: "memory");                                             \
    if ((K_) < 15) {                                                           \
      const char* aT = xqTB + aRowB + (size_t)(((K_) + 1) * 4) * GRANB;        \
      AN[0] = *(const i32x4*)(aT);                                             \
      AN[1] = *(const i32x4*)(aT + 256);                                       \
      AN[2] = *(const i32x4*)(aT + 512);                                       \
      AN[3] = *(const i32x4*)(aT + 768);                                       \
    } else if (hasNext) {                                                      \
      const char* aT = xqTB + aRowBN;                                          \
      AN[0] = *(const i32x4*)(aT);                                             \
      AN[1] = *(const i32x4*)(aT + 256);                                       \
      AN[2] = *(const i32x4*)(aT + 512);                                       \
      AN[3] = *(const i32x4*)(aT + 768);                                       \
    }                                                                          \
    if ((K_) < 13) {                                                           \
      const size_t bG = bPan + (size_t)(((K_) + 3) * 64);                      \
      SGB(bG, (((K_) + 3) & 3) * 16384);                                       \
      SGB(bG + 131072, (((K_) + 3) & 3) * 16384 + 8192);                       \
    } else if (hasNext) {                                                      \
      const size_t bG = bPanN + (size_t)(((K_)-13) * 64);                      \
      SGB(bG, (((K_) + 3) & 3) * 16384);                                       \
      SGB(bG + 131072, (((K_) + 3) & 3) * 16384 + 8192);                       \
    }                                                                          \
    i32x4 bb[4];                                                               \
    _Pragma("unroll") for (int n = 0; n < 4; ++n) bb[n] =                      \
        *(const i32x4*)(lds + ((K_)&3) * 16384 + bOff[n]);                     \
    __builtin_amdgcn_s_setprio(1);                                             \
    _Pragma("unroll") for (int n = 0; n < 4; ++n) {                            \
      acc[0][n] = __builtin_amdgcn_mfma_i32_16x16x64_i8(AC[0], bb[n],          \
                                                        acc[0][n], 0, 0, 0);   \
      acc[1][n] = __builtin_amdgcn_mfma_i32_16x16x64_i8(AC[1], bb[n],          \
                                                        acc[1][n], 0, 0, 0);   \
      acc[2][n] = __builtin_amdgcn_mfma_i32_16x16x64_i8(AC[2], bb[n],          \
                                                        acc[2][n], 0, 0, 0);   \
      acc[3][n] = __builtin_amdgcn_mfma_i32_16x16x64_i8(AC[3], bb[n],          \
                                                        acc[3][n], 0, 0, 0);   \
    }                                                                          \
    __builtin_amdgcn_s_setprio(0);                                             \
    _Pragma("unroll") for (int n = 0; n < 4; ++n) bb[n] =                      \
        *(const i32x4*)(lds + ((K_)&3) * 16384 + bOff[4 + n]);                 \
    __builtin_amdgcn_s_setprio(1);                                             \
    _Pragma("unroll") for (int n = 0; n < 4; ++n) {                            \
      acc[0][4 + n] = __builtin_amdgcn_mfma_i32_16x16x64_i8(                   \
          AC[0], bb[n], acc[0][4 + n], 0, 0, 0);                               \
      acc[1][4 + n] = __builtin_amdgcn_mfma_i32_16x16x64_i8(                   \
          AC[1], bb[n], acc[1][4 + n], 0, 0, 0);                               \
      acc[2][4 + n] = __builtin_amdgcn_mfma_i32_16x16x64_i8(                   \
          AC[2], bb[n], acc[2][4 + n], 0, 0, 0);                               \
      acc[3][4 + n] = __builtin_amdgcn_mfma_i32_16x16x64_i8(                   \
          AC[3], bb[n], acc[3][4 + n], 0, 0, 0);                               \
    }                                                                          \
    __builtin_amdgcn_s_setprio(0);                                             \
    asm volatile("s_waitcnt vmcnt(8)" ::: "memory");                           \
  }

__global__ __launch_bounds__(512, 2) void k_argmax(
    const signed char* __restrict__ xq, const signed char* __restrict__ xqT,
    u64* __restrict__ best, int* __restrict__ ctr) {
  extern __shared__ char lds[];
  int* s_next = (int*)(lds + 65536);  // 2 parity slots
  const char* xqB = (const char*)xq;
  const char* xqTB = (const char*)xqT;
  const int tid = (int)threadIdx.x, lane = tid & 63, w = tid >> 6;
  const int wr = w >> 1, wc = w & 1;

  // B slot (16KB): 256 rows x 64B, 2 rows/128B line,
  // granule swizzle: inner = (((rr&1)<<6)|(q<<4)) ^ ((line&7)<<4)
  int bOff[8];
  const int q = lane >> 4, li = lane & 15;
#pragma unroll
  for (int nf = 0; nf < 8; ++nf) {
    const int rr = wc * 128 + nf * 16 + li;
    const int line = rr >> 1;
    bOff[nf] = line * 128 + ((((rr & 1) << 6) | (q << 4)) ^ ((line & 7) << 4));
  }
  // staging per-lane source offset (inverse swizzle; linear gload dest)
  const int posx = (lane & 7) ^ (lane >> 3);
  const int rrl = ((w * 8 + (lane >> 3)) << 1) | (posx >> 2);
  const int srcLane = rrl * 1024 + (posx & 3) * 16;

  const int rB2 = wr * 64 + (q << 2);
  const int cB2 = wc * 128 + li;

  // bootstrap: steal first two pairs
  if (tid == 0) {
    s_next[0] = atomicAdd(ctr, 1);
    s_next[1] = atomicAdd(ctr, 1);
  }
  __syncthreads();
  int pcur = s_next[0], pnext = s_next[1];
  __syncthreads();
  if (pcur >= NPAIRS) return;

  int a, b;
  decode_pair(pcur, a, b);
  size_t bPan = (size_t)b * PANB;
  size_t aRowB = (size_t)q * GRANB + (size_t)(a * 256 + wr * 64 + li) * 16;

  i32x4 aaA[4], aaB[4];
  // prologue: A prefetch tile 0 -> aaA, then B stage tiles 0..2
  {
    const char* aT = xqTB + aRowB;
    aaA[0] = *(const i32x4*)(aT);
    aaA[1] = *(const i32x4*)(aT + 256);
    aaA[2] = *(const i32x4*)(aT + 512);
    aaA[3] = *(const i32x4*)(aT + 768);
  }
  for (int p = 0; p < 3; ++p) {
    SGB(bPan + (size_t)(p * 64), p * 16384);
    SGB(bPan + (size_t)(p * 64) + 131072, p * 16384 + 8192);
  }
  asm volatile("s_waitcnt vmcnt(4)" ::: "memory");

  int par = 0;
  i32x4 acc[4][8];
  while (true) {
    const bool hasNext = (pnext < NPAIRS);
    int an = 0, bn = 0;
    if (hasNext) decode_pair(pnext, an, bn);
    const size_t bPanN = (size_t)bn * PANB;
    const size_t aRowBN =
        (size_t)q * GRANB + (size_t)(an * 256 + wr * 64 + li) * 16;
    if (tid == 0) s_next[par] = atomicAdd(ctr, 1);  // steal pair-after-next

#pragma unroll
    for (int m = 0; m < 4; ++m)
#pragma unroll
      for (int n = 0; n < 8; ++n) acc[m][n] = (i32x4){0, 0, 0, 0};

    KT1(0, aaA, aaB) KT1(1, aaB, aaA) KT1(2, aaA, aaB) KT1(3, aaB, aaA)
    KT1(4, aaA, aaB) KT1(5, aaB, aaA) KT1(6, aaA, aaB) KT1(7, aaB, aaA)
    KT1(8, aaA, aaB) KT1(9, aaB, aaA) KT1(10, aaA, aaB) KT1(11, aaB, aaA)
    KT1(12, aaA, aaB) KT1(13, aaB, aaA) KT1(14, aaA, aaB) KT1(15, aaB, aaA)

    // ---- epilogue for pair (a,b): register folds + atomicMax publish ----
    const int aBase = a * 256, colBase = b * 256;
    // row-side: rows of a over cols of b
#pragma unroll
    for (int m = 0; m < 4; ++m)
#pragma unroll
      for (int r = 0; r < 4; ++r) {
        const int rl = rB2 + m * 16 + r;
        int pm = (int)0x80000000;
        if (a == b) {
#pragma unroll
          for (int nf = 0; nf < 8; ++nf) {
            int pv = (int)(((u32)acc[m][nf][r] << 3) | (u32)nf);
            if (rl == cB2 + nf * 16) pv = (int)0x80000000;
            pm = pm > pv ? pm : pv;
          }
        } else {
#pragma unroll
          for (int nf = 0; nf < 8; ++nf) {
            const int pv = (int)(((u32)acc[m][nf][r] << 3) | (u32)nf);
            pm = pm > pv ? pm : pv;
          }
        }
        const u32 mono = (u32)(pm >> 3) ^ 0x80000000u;
        u64 p = ((u64)mono << 32) | (u32)(colBase + cB2 + ((pm & 7) << 4));
#pragma unroll
        for (int sh = 1; sh < 16; sh <<= 1)
          p = maxu64(p, __shfl_xor(p, sh, 64));
        if (li == 0) atomicMax(best + (aBase + rl), p);
      }

    // col-side: rows of b, candidates = rows of a (skip on diagonal)
    if (a != b) {
#pragma unroll
      for (int nf = 0; nf < 8; ++nf) {
        int pv = (int)0x80000000;
#pragma unroll
        for (int m = 0; m < 4; ++m)
#pragma unroll
          for (int r = 0; r < 4; ++r) {
            const int c =
                (int)(((u32)acc[m][nf][r] << 6) | (u32)(m * 16 + q * 4 + r));
            pv = pv > c ? pv : c;
          }
        {
          const int o1 = __shfl_xor(pv, 16, 64);
          pv = pv > o1 ? pv : o1;
          const int o2 = __shfl_xor(pv, 32, 64);
          pv = pv > o2 ? pv : o2;
        }
        if (q == 0) {
          const int dot = pv >> 6;
          const int grow = aBase + wr * 64 + (pv & 63);
          const u64 pk = ((u64)((u32)dot ^ 0x80000000u) << 32) | (u32)grow;
          atomicMax(best + (colBase + cB2 + nf * 16), pk);
        }
      }
    }

    if (!hasNext) break;
    const int pnn = s_next[par];  // published by the KT barriers
    pcur = pnext;
    a = an;
    b = bn;
    bPan = bPanN;
    aRowB = aRowBN;
    pnext = pnn;
    par ^= 1;
  }
}

// ---------- kernel 3: exact fp32 distance + log ----------

__global__ __launch_bounds__(256) void k_dist(
    const float* __restrict__ x, const float* __restrict__ norms,
    const u64* __restrict__ best, float* __restrict__ logd) {
  const int w = threadIdx.x >> 6, lane = threadIdx.x & 63;
  const int i = blockIdx.x * 4 + w;
  const u64 p = best[i];
  const int j = (int)(p & 0xffffffffu);
  const float invi = 1.f / fmaxf(norms[i], EPSF);
  const float invj = 1.f / fmaxf(norms[j], EPSF);
  const float4* xi = (const float4*)(x + (size_t)i * D);
  const float4* xj = (const float4*)(x + (size_t)j * D);
  float s = 0.f;
#pragma unroll
  for (int t = 0; t < 4; ++t) {
    const float4 av = xi[lane + t * 64], bv = xj[lane + t * 64];
    float d;
    d = av.x * invi - bv.x * invj + EPSF; s += d * d;
    d = av.y * invi - bv.y * invj + EPSF; s += d * d;
    d = av.z * invi - bv.z * invj + EPSF; s += d * d;
    d = av.w * invi - bv.w * invj + EPSF; s += d * d;
  }
#pragma unroll
  for (int sh = 32; sh; sh >>= 1) s += __shfl_xor(s, sh, 64);
  if (lane == 0) logd[i] = logf(sqrtf(s) + EPSF);
}

// ---------- kernel 4: deterministic fixed-order mean ----------

__global__ __launch_bounds__(256) void k_final(const float* __restrict__ logd,
                                               float* __restrict__ out) {
  __shared__ double red[256];
  double s = 0.0;
  for (int i = threadIdx.x; i < N; i += 256) s += (double)logd[i];
  red[threadIdx.x] = s;
  __syncthreads();
  for (int sh = 128; sh; sh >>= 1) {
    if ((int)threadIdx.x < sh) red[threadIdx.x] += red[threadIdx.x + sh];
    __syncthreads();
  }
  if (threadIdx.x == 0) out[0] = (float)(-red[0] / (double)N);
}

// ---------- launch ----------

extern "C" void kernel_launch(void* const* d_in, const int* in_sizes, int n_in,
                              void* d_out, int out_size, void* d_ws,
                              size_t ws_size, hipStream_t stream) {
  const float* x = (const float*)d_in[0];
  float* out = (float*)d_out;
  char* ws = (char*)d_ws;

  // ws: xq 16MB | xqT 16MB | norms 64KB | best 128KB | logd 64KB | ctr 64B
  signed char* xq = (signed char*)ws;
  signed char* xqT = (signed char*)(ws + 16777216);
  float* norms = (float*)(ws + 33554432);
  u64* best = (u64*)(ws + 33619968);
  float* logd = (float*)(ws + 33751040);
  int* ctr = (int*)(ws + 33816576);

  k_normalize<<<N / 4, 256, 0, stream>>>(x, xq, xqT, norms, best, ctr);
  k_argmax<<<256, 512, LDS_TOT, stream>>>(xq, xqT, best, ctr);
  k_dist<<<N / 4, 256, 0, stream>>>(x, norms, best, logd);
  k_final<<<1, 256, 0, stream>>>(logd, out);
}

// Round 12
// 217.275 us; speedup vs baseline: 1.2844x; 1.1985x over previous
//
#include <hip/hip_runtime.h>
#include <math.h>

#define N 16384
#define D 1024
#define EPSF 1e-8f
#define QSCALE 448.0f
#define NPAIRS 2080
#define NBLK 256
#define PANB 262144 /* bytes per 256-row i8 panel */
#define BIAS 16777216u

typedef __attribute__((ext_vector_type(4))) int i32x4;
typedef unsigned int u32;
typedef unsigned long long u64;

// LDS: A ring4 [0,64K), B ring4 [64K,128K)
#define LDS_Bb 65536
#define LDS_TOT 131072

__device__ __forceinline__ void gload_lds16(const void* g, void* l) {
  __builtin_amdgcn_global_load_lds(
      (const __attribute__((address_space(1))) u32*)g,
      (__attribute__((address_space(3))) u32*)l, 16, 0, 0);
}

__device__ __forceinline__ u64 maxu64(u64 x, u64 y) { return x > y ? x : y; }
__device__ __forceinline__ int maxi(int x, int y) { return x > y ? x : y; }

__device__ __forceinline__ void decode_pair(int t, int& a, int& b) {
  int aa = (int)((129.0 - sqrt(129.0 * 129.0 - 8.0 * (double)t)) * 0.5);
  if (aa < 0) aa = 0;
  if (aa > 63) aa = 63;
  while (((aa + 1) * 64 - ((aa + 1) * aa) / 2) <= t) ++aa;
  while ((aa * 64 - (aa * (aa - 1)) / 2) > t) --aa;
  a = aa;
  b = aa + (t - (aa * 64 - (aa * (aa - 1)) / 2));
}

// ---------- kernel 1: norms + globally-scaled i8 matrix + zero best ----------

__global__ __launch_bounds__(256) void k_normalize(
    const float* __restrict__ x, signed char* __restrict__ xq,
    float* __restrict__ norms, u64* __restrict__ best) {
  const int w = threadIdx.x >> 6, lane = threadIdx.x & 63;
  const int i = blockIdx.x * 4 + w;  // one wave per row
  if (threadIdx.x < 4) best[(size_t)blockIdx.x * 4 + threadIdx.x] = 0;
  const float4* xi = (const float4*)(x + (size_t)i * D);
  float4 v[4];
  float s = 0.f;
#pragma unroll
  for (int t = 0; t < 4; ++t) {
    v[t] = xi[lane + t * 64];
    s += v[t].x * v[t].x + v[t].y * v[t].y + v[t].z * v[t].z + v[t].w * v[t].w;
  }
#pragma unroll
  for (int sh = 32; sh; sh >>= 1) s += __shfl_xor(s, sh, 64);
  const float nrm = sqrtf(s);
  if (lane == 0) norms[i] = nrm;
  const float qs = QSCALE / fmaxf(nrm, EPSF);
  u32* xo = (u32*)(xq + (size_t)i * D);
#pragma unroll
  for (int t = 0; t < 4; ++t) {
    const int q0 = __float2int_rn(fminf(fmaxf(v[t].x * qs, -127.f), 127.f));
    const int q1 = __float2int_rn(fminf(fmaxf(v[t].y * qs, -127.f), 127.f));
    const int q2 = __float2int_rn(fminf(fmaxf(v[t].z * qs, -127.f), 127.f));
    const int q3 = __float2int_rn(fminf(fmaxf(v[t].w * qs, -127.f), 127.f));
    xo[lane + t * 64] = (u32)(q0 & 0xff) | ((u32)(q1 & 0xff) << 8) |
                        ((u32)(q2 & 0xff) << 16) | ((u32)(q3 & 0xff) << 24);
  }
}

// ---------- kernel 2: chunked symmetric-pair i8 MFMA argmax (rolled loop) ----------
// 256 blocks; block c owns pairs [c*2080/256,(c+1)*2080/256) in (a,b)-lex
// order (A-panel L2-hot across the chunk). 512 thr = 8 waves (4M x 2N),
// per-wave C = 64x128. Rolled kq loop, 4 compile-time-slot KTs per iter,
// ring-4 LDS, stage 3 tiles ahead rolling into the next pair, 1 barrier +
// counted vmcnt(8) per K-tile. Compact 32-bit packed epilogue per pair;
// deterministic u64 atomicMax publish (order-independent max).

#define SGB(gaddr, daddr) \
  gload_lds16(xqB + (gaddr) + srcLane, lds + (daddr) + w * 1024)

#define KT(C_)                                                                 \
  {                                                                            \
    const int k_ = kq * 4 + (C_);                                              \
    const int t_ = k_ + 3;                                                     \
    const int kt_ = t_ & 15;                                                   \
    const size_t aG = (t_ >= 16 ? aPanN : aPan) + (size_t)(kt_ * 64);          \
    const size_t bG = (t_ >= 16 ? bPanN : bPan) + (size_t)(kt_ * 64);          \
    __builtin_amdgcn_s_barrier();                                              \
    asm volatile("" ::: "memory");                                             \
    SGB(aG, (((C_) + 3) & 3) * 16384);                                         \
    SGB(aG + 131072, (((C_) + 3) & 3) * 16384 + 8192);                         \
    SGB(bG, LDS_Bb + (((C_) + 3) & 3) * 16384);                                \
    SGB(bG + 131072, LDS_Bb + (((C_) + 3) & 3) * 16384 + 8192);                \
    i32x4 aa[4], bb[4];                                                        \
    _Pragma("unroll") for (int m = 0; m < 4; ++m) aa[m] =                      \
        *(const i32x4*)(lds + ((C_)&3) * 16384 + aOff[m]);                     \
    _Pragma("unroll") for (int n = 0; n < 4; ++n) bb[n] =                      \
        *(const i32x4*)(lds + LDS_Bb + ((C_)&3) * 16384 + bOff[n]);            \
    __builtin_amdgcn_s_setprio(1);                                             \
    _Pragma("unroll") for (int m = 0; m < 4; ++m)                              \
      _Pragma("unroll") for (int n = 0; n < 4; ++n)                            \
        acc[m][n] = __builtin_amdgcn_mfma_i32_16x16x64_i8(aa[m], bb[n],        \
                                                          acc[m][n], 0, 0, 0); \
    __builtin_amdgcn_s_setprio(0);                                             \
    _Pragma("unroll") for (int n = 0; n < 4; ++n) bb[n] =                      \
        *(const i32x4*)(lds + LDS_Bb + ((C_)&3) * 16384 + bOff[4 + n]);        \
    __builtin_amdgcn_s_setprio(1);                                             \
    _Pragma("unroll") for (int m = 0; m < 4; ++m)                              \
      _Pragma("unroll") for (int n = 0; n < 4; ++n)                            \
        acc[m][4 + n] = __builtin_amdgcn_mfma_i32_16x16x64_i8(                 \
            aa[m], bb[n], acc[m][4 + n], 0, 0, 0);                             \
    __builtin_amdgcn_s_setprio(0);                                             \
    asm volatile("s_waitcnt vmcnt(8)" ::: "memory");                           \
  }

__global__ __launch_bounds__(512, 2) void k_argmax(
    const signed char* __restrict__ xq, u64* __restrict__ best) {
  extern __shared__ char lds[];
  const char* xqB = (const char*)xq;
  const int tid = (int)threadIdx.x, lane = tid & 63, w = tid >> 6;
  const int wr = w >> 1, wc = w & 1;

  // LDS slot (16KB): 256 rows x 64B, 2 rows/128B line,
  // granule swizzle: inner = (((rr&1)<<6)|(q<<4)) ^ ((line&7)<<4)
  int aOff[4], bOff[8];
  const int q = lane >> 4, li = lane & 15;
#pragma unroll
  for (int m = 0; m < 4; ++m) {
    const int rr = wr * 64 + m * 16 + li;
    const int line = rr >> 1;
    aOff[m] = line * 128 + ((((rr & 1) << 6) | (q << 4)) ^ ((line & 7) << 4));
  }
#pragma unroll
  for (int nf = 0; nf < 8; ++nf) {
    const int rr = wc * 128 + nf * 16 + li;
    const int line = rr >> 1;
    bOff[nf] = line * 128 + ((((rr & 1) << 6) | (q << 4)) ^ ((line & 7) << 4));
  }
  // staging per-lane source offset (inverse swizzle; linear gload dest)
  const int posx = (lane & 7) ^ (lane >> 3);
  const int rrl = ((w * 8 + (lane >> 3)) << 1) | (posx >> 2);
  const int srcLane = rrl * 1024 + (posx & 3) * 16;

  const int rB2 = wr * 64 + (q << 2);
  const int cB2 = wc * 128 + li;

  // static chunk of the triangle pair list
  const int p0 = ((int)blockIdx.x * NPAIRS) / NBLK;
  const int p1 = (((int)blockIdx.x + 1) * NPAIRS) / NBLK;
  int a, b;
  decode_pair(p0, a, b);
  size_t aPan = (size_t)a * PANB, bPan = (size_t)b * PANB;

  // prologue: stage K-tiles 0..2 into ring slots 0..2
  for (int pp = 0; pp < 3; ++pp) {
    SGB(aPan + (size_t)(pp * 64), pp * 16384);
    SGB(aPan + (size_t)(pp * 64) + 131072, pp * 16384 + 8192);
    SGB(bPan + (size_t)(pp * 64), LDS_Bb + pp * 16384);
    SGB(bPan + (size_t)(pp * 64) + 131072, LDS_Bb + pp * 16384 + 8192);
  }
  asm volatile("s_waitcnt vmcnt(8)" ::: "memory");

  i32x4 acc[4][8];
  for (int p = p0; p < p1; ++p) {
    // next pair (dup-stage own panels on the last pair -- harmless)
    int an = a, bn = b + 1;
    if (bn == 64) {
      an = a + 1;
      bn = an;
    }
    const bool lastp = (p == p1 - 1);
    const size_t aPanN = lastp ? aPan : (size_t)an * PANB;
    const size_t bPanN = lastp ? bPan : (size_t)bn * PANB;

#pragma unroll
    for (int m = 0; m < 4; ++m)
#pragma unroll
      for (int n = 0; n < 8; ++n) acc[m][n] = (i32x4){0, 0, 0, 0};

    for (int kq = 0; kq < 4; ++kq) {
      KT(0)
      KT(1)
      KT(2)
      KT(3)
    }

    // ---- epilogue: 32-bit packed folds, u64 atomicMax publish ----
    const int aBase = a * 256, colBase = b * 256;
    // row-side: rows of a over cols of b.
    // pack: ((dot + 2^24) << 7) | (nf<<4|li); dot+2^24 < 2^25 -> exact 32-bit
#pragma unroll
    for (int m = 0; m < 4; ++m)
#pragma unroll
      for (int r = 0; r < 4; ++r) {
        const int rl = rB2 + m * 16 + r;
        int pk = 0;  // masked/min sentinel (all valid packs > 0)
        if (a == b) {
#pragma unroll
          for (int nf = 0; nf < 8; ++nf) {
            int v = (int)((((u32)acc[m][nf][r] + BIAS) << 7) |
                          (u32)((nf << 4) | li));
            if (rl == cB2 + nf * 16) v = 0;
            pk = maxi(pk, v);
          }
        } else {
#pragma unroll
          for (int nf = 0; nf < 8; ++nf) {
            const int v = (int)((((u32)acc[m][nf][r] + BIAS) << 7) |
                                (u32)((nf << 4) | li));
            pk = maxi(pk, v);
          }
        }
#pragma unroll
        for (int sh = 1; sh < 16; sh <<= 1) pk = maxi(pk, __shfl_xor(pk, sh, 64));
        if (li == 0) {
          const int dot = (int)((((u32)pk) >> 7) - BIAS);
          const int col = colBase + wc * 128 + (pk & 127);
          const u64 key = ((u64)((u32)dot ^ 0x80000000u) << 32) | (u32)col;
          atomicMax(best + (aBase + rl), key);
        }
      }

    // col-side: rows of b, candidates = rows of a (skip on diagonal).
    // pack: ((dot + 2^24) << 6) | (m*16 + q*4 + r)  -> 31 bits, exact
    if (a != b) {
#pragma unroll
      for (int nf = 0; nf < 8; ++nf) {
        int pk = 0;
#pragma unroll
        for (int m = 0; m < 4; ++m)
#pragma unroll
          for (int r = 0; r < 4; ++r) {
            const int v = (int)((((u32)acc[m][nf][r] + BIAS) << 6) |
                                (u32)(m * 16 + q * 4 + r));
            pk = maxi(pk, v);
          }
        pk = maxi(pk, __shfl_xor(pk, 16, 64));
        pk = maxi(pk, __shfl_xor(pk, 32, 64));
        if (q == 0) {
          const int dot = (int)((((u32)pk) >> 6) - BIAS);
          const int grow = aBase + wr * 64 + (pk & 63);
          const u64 key = ((u64)((u32)dot ^ 0x80000000u) << 32) | (u32)grow;
          atomicMax(best + (colBase + cB2 + nf * 16), key);
        }
      }
    }

    a = an;
    b = bn;
    aPan = (size_t)a * PANB;
    bPan = (size_t)b * PANB;
  }
}

// ---------- kernel 3: exact fp32 distance + log ----------

__global__ __launch_bounds__(256) void k_dist(
    const float* __restrict__ x, const float* __restrict__ norms,
    const u64* __restrict__ best, float* __restrict__ logd) {
  const int w = threadIdx.x >> 6, lane = threadIdx.x & 63;
  const int i = blockIdx.x * 4 + w;
  const u64 p = best[i];
  const int j = (int)(p & 0xffffffffu);
  const float invi = 1.f / fmaxf(norms[i], EPSF);
  const float invj = 1.f / fmaxf(norms[j], EPSF);
  const float4* xi = (const float4*)(x + (size_t)i * D);
  const float4* xj = (const float4*)(x + (size_t)j * D);
  float s = 0.f;
#pragma unroll
  for (int t = 0; t < 4; ++t) {
    const float4 av = xi[lane + t * 64], bv = xj[lane + t * 64];
    float d;
    d = av.x * invi - bv.x * invj + EPSF; s += d * d;
    d = av.y * invi - bv.y * invj + EPSF; s += d * d;
    d = av.z * invi - bv.z * invj + EPSF; s += d * d;
    d = av.w * invi - bv.w * invj + EPSF; s += d * d;
  }
#pragma unroll
  for (int sh = 32; sh; sh >>= 1) s += __shfl_xor(s, sh, 64);
  if (lane == 0) logd[i] = logf(sqrtf(s) + EPSF);
}

// ---------- kernel 4: deterministic fixed-order mean ----------

__global__ __launch_bounds__(256) void k_final(const float* __restrict__ logd,
                                               float* __restrict__ out) {
  __shared__ double red[256];
  double s = 0.0;
  for (int i = threadIdx.x; i < N; i += 256) s += (double)logd[i];
  red[threadIdx.x] = s;
  __syncthreads();
  for (int sh = 128; sh; sh >>= 1) {
    if ((int)threadIdx.x < sh) red[threadIdx.x] += red[threadIdx.x + sh];
    __syncthreads();
  }
  if (threadIdx.x == 0) out[0] = (float)(-red[0] / (double)N);
}

// ---------- launch ----------

extern "C" void kernel_launch(void* const* d_in, const int* in_sizes, int n_in,
                              void* d_out, int out_size, void* d_ws,
                              size_t ws_size, hipStream_t stream) {
  const float* x = (const float*)d_in[0];
  float* out = (float*)d_out;
  char* ws = (char*)d_ws;

  // ws: xq 16MB | norms 64KB | best N*8 = 128KB | logd 64KB
  signed char* xq = (signed char*)ws;
  float* norms = (float*)(ws + 16777216);
  u64* best = (u64*)(ws + 16842752);
  float* logd = (float*)(ws + 16973824);

  k_normalize<<<N / 4, 256, 0, stream>>>(x, xq, norms, best);
  k_argmax<<<NBLK, 512, LDS_TOT, stream>>>(xq, best);
  k_dist<<<N / 4, 256, 0, stream>>>(x, norms, best, logd);
  k_final<<<1, 256, 0, stream>>>(logd, out);
}